// Round 22
// baseline (590.609 us; speedup 1.0000x reference)
//
#include <hip/hip_runtime.h>
#include <hip/hip_bf16.h>

#define N_NODES 100000
#define N_EDGES 1600000
#define IN_DIM  128
#define HID     64
#define N_GRAPHS 500

// bf16 helpers (RNE pack, shift unpack)
__device__ inline unsigned short f2bf(float f) {
    unsigned u = __float_as_uint(f);
    u += 0x7FFFu + ((u >> 16) & 1u);
    return (unsigned short)(u >> 16);
}
__device__ inline float bf2f(unsigned short b) {
    return __uint_as_float(((unsigned)b) << 16);
}

// dot(q[node], k_row) with q distributed 2 elems/lane over a 32-lane group:
// lane l holds q[2l] (qreg.x), q[2l+1] (qreg.y). k_row local to this lane.
__device__ inline float dot64_q2_bf16(float2 qreg, const unsigned short* __restrict__ krow) {
    const uint4* kp = (const uint4*)krow;
    uint4 kr[8];
    #pragma unroll
    for (int i = 0; i < 8; ++i) kr[i] = kp[i];
    float dot = 0.f;
    #pragma unroll
    for (int i = 0; i < 8; ++i) {
        #pragma unroll
        for (int c = 0; c < 4; ++c) {
            unsigned w = (&kr[i].x)[c];          // cols 8i+2c, 8i+2c+1
            float qa = __shfl(qreg.x, 4 * i + c, 32);
            float qb = __shfl(qreg.y, 4 * i + c, 32);
            dot = fmaf(qa, __uint_as_float(w << 16), dot);
            dot = fmaf(qb, __uint_as_float(w & 0xFFFF0000u), dot);
        }
    }
    return dot;
}

// ============ shared GEMM body (64x64 C-tile of ONE matrix; 4x4 micro-tile) ====
// DIN=64: single BK=64 stage (1 barrier round); DIN=128: two BK=32 stages.
template<int DIN>
__device__ inline void gemm_body(
    int by, int ty_blk,
    const float* __restrict__ x, int N,
    const float* __restrict__ Wq, const float* __restrict__ bq,
    const float* __restrict__ Wk, const float* __restrict__ bk,
    const float* __restrict__ Wv, const float* __restrict__ bv,
    const float* __restrict__ Ws, const float* __restrict__ bs,
    float* __restrict__ q, unsigned short* __restrict__ kb,
    unsigned short* __restrict__ vb, float* __restrict__ hout)
{
    constexpr int BM = 64;
    constexpr int BK = (DIN == 64) ? 64 : 32;
    constexpr int D4 = BK / 4;                 // float4 per x-tile row
    __shared__ float As[BK][BM + 1];
    __shared__ float Bs[BK][64];

    const float* W    = (by == 0) ? Wq : (by == 1) ? Wk : (by == 2) ? Wv : Ws;
    const float* bias = (by == 0) ? bq : (by == 1) ? bk : (by == 2) ? bv : bs;

    const int row0 = ty_blk * BM;
    const int tid  = threadIdx.x;
    const int tx   = (tid & 15) * 4;
    const int ty   = (tid >> 4) * 4;

    float acc[4][4] = {};

    for (int k0 = 0; k0 < DIN; k0 += BK) {
        #pragma unroll
        for (int h = 0; h < (64 * D4) / 256; ++h) {
            int idx = tid + h * 256;
            int r   = idx / D4, c4 = idx % D4;
            int gr  = row0 + r;
            float4 val = (gr < N) ? *(const float4*)(x + (size_t)gr * DIN + k0 + c4 * 4)
                                  : make_float4(0.f, 0.f, 0.f, 0.f);
            int kk = c4 * 4;
            As[kk + 0][r] = val.x;
            As[kk + 1][r] = val.y;
            As[kk + 2][r] = val.z;
            As[kk + 3][r] = val.w;
        }
        #pragma unroll
        for (int h = 0; h < (BK * 16) / 256; ++h) {
            int idx = tid + h * 256;
            int kr  = idx >> 4, n4 = (idx & 15) * 4;
            *(float4*)(&Bs[kr][n4]) = *(const float4*)(W + (size_t)(k0 + kr) * 64 + n4);
        }
        __syncthreads();

        #pragma unroll 8
        for (int kk = 0; kk < BK; ++kk) {
            float4 a = *(const float4*)(&As[kk][ty]);
            float4 b = *(const float4*)(&Bs[kk][tx]);
            acc[0][0] = fmaf(a.x, b.x, acc[0][0]);
            acc[0][1] = fmaf(a.x, b.y, acc[0][1]);
            acc[0][2] = fmaf(a.x, b.z, acc[0][2]);
            acc[0][3] = fmaf(a.x, b.w, acc[0][3]);
            acc[1][0] = fmaf(a.y, b.x, acc[1][0]);
            acc[1][1] = fmaf(a.y, b.y, acc[1][1]);
            acc[1][2] = fmaf(a.y, b.z, acc[1][2]);
            acc[1][3] = fmaf(a.y, b.w, acc[1][3]);
            acc[2][0] = fmaf(a.z, b.x, acc[2][0]);
            acc[2][1] = fmaf(a.z, b.y, acc[2][1]);
            acc[2][2] = fmaf(a.z, b.z, acc[2][2]);
            acc[2][3] = fmaf(a.z, b.w, acc[2][3]);
            acc[3][0] = fmaf(a.w, b.x, acc[3][0]);
            acc[3][1] = fmaf(a.w, b.y, acc[3][1]);
            acc[3][2] = fmaf(a.w, b.z, acc[3][2]);
            acc[3][3] = fmaf(a.w, b.w, acc[3][3]);
        }
        __syncthreads();
    }

    float4 bv4 = *(const float4*)(bias + tx);
    if (by == 1 || by == 2) {
        unsigned short* op = (by == 1) ? kb : vb;
        #pragma unroll
        for (int i = 0; i < 4; ++i) {
            int row = row0 + ty + i;
            if (row < N) {
                ushort4 pk;
                pk.x = f2bf(acc[i][0] + bv4.x);
                pk.y = f2bf(acc[i][1] + bv4.y);
                pk.z = f2bf(acc[i][2] + bv4.z);
                pk.w = f2bf(acc[i][3] + bv4.w);
                *(ushort4*)(op + (size_t)row * 64 + tx) = pk;
            }
        }
    } else {
        float* op = (by == 0) ? q : hout;
        #pragma unroll
        for (int i = 0; i < 4; ++i) {
            int row = row0 + ty + i;
            if (row < N) {
                float4 o = make_float4(acc[i][0] + bv4.x, acc[i][1] + bv4.y,
                                       acc[i][2] + bv4.z, acc[i][3] + bv4.w);
                *(float4*)(op + (size_t)row * 64 + tx) = o;
            }
        }
    }
}

// ============ CSR build ============
__global__ void zero_i(int* p, int n) {
    int i = blockIdx.x * blockDim.x + threadIdx.x;
    if (i < n) p[i] = 0;
}

#define COUNT_BLOCKS 1024

// layer-0 GEMM fused with count_rank (count blocks first, simple grid-stride —
// the count phase is atomic-throughput-bound; unrolling it regressed (R20)).
__global__ __launch_bounds__(256) void gemm0_count(
    const float* __restrict__ x, int N,
    const float* __restrict__ Wq, const float* __restrict__ bq,
    const float* __restrict__ Wk, const float* __restrict__ bk,
    const float* __restrict__ Wv, const float* __restrict__ bv,
    const float* __restrict__ Ws, const float* __restrict__ bs,
    float* __restrict__ q, unsigned short* __restrict__ kb,
    unsigned short* __restrict__ vb, float* __restrict__ hout,
    const int* __restrict__ dst, int* __restrict__ counts,
    int* __restrict__ rank, int E)
{
    int bi = blockIdx.x;
    if (bi < COUNT_BLOCKS) {
        for (int e = bi * 256 + threadIdx.x; e < E; e += COUNT_BLOCKS * 256)
            rank[e] = atomicAdd(&counts[dst[e]], 1);
    } else {
        int gb = bi - COUNT_BLOCKS;
        gemm_body<IN_DIM>(gb & 3, gb >> 2, x, N, Wq, bq, Wk, bk, Wv, bv, Ws, bs,
                          q, kb, vb, hout);
    }
}

__global__ void scan1(const int* __restrict__ counts, int* __restrict__ pre,
                      int* __restrict__ blockSums, int n) {
    __shared__ int tmp[256];
    int tid = threadIdx.x;
    int i = blockIdx.x * 256 + tid;
    int v = (i < n) ? counts[i] : 0;
    tmp[tid] = v; __syncthreads();
    int acc = v;
    for (int off = 1; off < 256; off <<= 1) {
        int add = (tid >= off) ? tmp[tid - off] : 0;
        __syncthreads();
        acc += add; tmp[tid] = acc;
        __syncthreads();
    }
    if (i < n) pre[i] = acc - v;
    if (tid == 255) blockSums[blockIdx.x] = acc;
}

__global__ void scan2(int* blockSums, int nb) {
    __shared__ int tmp[512];
    int tid = threadIdx.x;
    int v = (tid < nb) ? blockSums[tid] : 0;
    tmp[tid] = v; __syncthreads();
    int acc = v;
    for (int off = 1; off < 512; off <<= 1) {
        int add = (tid >= off) ? tmp[tid - off] : 0;
        __syncthreads();
        acc += add; tmp[tid] = acc;
        __syncthreads();
    }
    if (tid < nb) blockSums[tid] = acc - v;
}

__global__ void scan3(const int* __restrict__ pre, const int* __restrict__ blockSums,
                      int* __restrict__ row_start, int n, int E) {
    int i = blockIdx.x * blockDim.x + threadIdx.x;
    if (i < n) {
        row_start[i] = pre[i] + blockSums[i >> 8];
    } else if (i == n) {
        row_start[n] = E;
    }
}

// atomic-free scatter, 4 edges/thread: int4 index loads, 4 gathers+stores in flight
__global__ void csr_scatter(const int* __restrict__ src, const int* __restrict__ dst,
                            const int* __restrict__ rank, const int* __restrict__ row_start,
                            int* __restrict__ csr_src, int E) {
    int e0 = (blockIdx.x * blockDim.x + threadIdx.x) * 4;
    if (e0 + 3 < E) {
        int4 d = *(const int4*)(dst + e0);
        int4 r = *(const int4*)(rank + e0);
        int4 s = *(const int4*)(src + e0);
        int p0 = row_start[d.x] + r.x;
        int p1 = row_start[d.y] + r.y;
        int p2 = row_start[d.z] + r.z;
        int p3 = row_start[d.w] + r.w;
        csr_src[p0] = s.x;
        csr_src[p1] = s.y;
        csr_src[p2] = s.z;
        csr_src[p3] = s.w;
    } else {
        for (int e = e0; e < E; ++e)
            csr_src[row_start[dst[e]] + rank[e]] = src[e];
    }
}

// ============ standalone qkvs GEMM (layers 1..2) ============
template<int DIN>
__global__ __launch_bounds__(256) void qkvs_gemm(
    const float* __restrict__ x, int N,
    const float* __restrict__ Wq, const float* __restrict__ bq,
    const float* __restrict__ Wk, const float* __restrict__ bk,
    const float* __restrict__ Wv, const float* __restrict__ bv,
    const float* __restrict__ Ws, const float* __restrict__ bs,
    float* __restrict__ q, unsigned short* __restrict__ kb,
    unsigned short* __restrict__ vb, float* __restrict__ hout)
{
    gemm_body<DIN>(blockIdx.x, blockIdx.y, x, N, Wq, bq, Wk, bk, Wv, bv, Ws, bs,
                   q, kb, vb, hout);
}

// ============ fused scores + softmax + aggregation + skip + relu ============
// TWO nodes per wave (32 lanes each); deg<=32 fast path.
__global__ __launch_bounds__(256) void node_attn(
    const float* __restrict__ q, const unsigned short* __restrict__ kb,
    const unsigned short* __restrict__ vb,
    const int* __restrict__ csr_src, const int* __restrict__ row_start,
    float* __restrict__ csr_exp, float* __restrict__ hout, int N)
{
    int node = blockIdx.x * 8 + (threadIdx.x >> 5);
    int lane = threadIdx.x & 31;
    if (node >= N) return;
    int start = row_start[node], end = row_start[node + 1];
    int deg = end - start;
    size_t ob = (size_t)node * 64 + 2 * lane;

    float2 hv = *(const float2*)(hout + ob);   // skip path
    if (deg == 0) {
        hv.x = fmaxf(hv.x, 0.f); hv.y = fmaxf(hv.y, 0.f);
        *(float2*)(hout + ob) = hv;
        return;
    }

    float2 qreg = *(const float2*)(q + ob);    // q[node][2l..2l+1], coalesced
    float2 acc = make_float2(0.f, 0.f);

    if (deg <= 32) {
        int s_l = (lane < deg) ? csr_src[start + lane] : 0;
        float dot = dot64_q2_bf16(qreg, kb + (size_t)s_l * 64);
        float sc = (lane < deg) ? dot * 0.125f : -__builtin_inff();

        float m = sc;
        #pragma unroll
        for (int off = 1; off < 32; off <<= 1) m = fmaxf(m, __shfl_xor(m, off, 32));

        float ex = __expf(sc - m);     // lanes >= deg: exp(-inf)=0
        float ssum = ex;
        #pragma unroll
        for (int off = 1; off < 32; off <<= 1) ssum += __shfl_xor(ssum, off, 32);
        float alpha = ex * (1.f / (ssum + 1e-16f));

        int j = 0;
        for (; j + 16 <= deg; j += 16) {
            float a[16]; int s[16];
            #pragma unroll
            for (int t = 0; t < 16; ++t) {
                a[t] = __shfl(alpha, j + t, 32);
                s[t] = __shfl(s_l, j + t, 32);
            }
            unsigned w[16];
            #pragma unroll
            for (int t = 0; t < 16; ++t)
                w[t] = *(const unsigned*)(vb + (size_t)s[t] * 64 + 2 * lane);
            #pragma unroll
            for (int t = 0; t < 16; ++t) {
                acc.x = fmaf(a[t], __uint_as_float(w[t] << 16), acc.x);
                acc.y = fmaf(a[t], __uint_as_float(w[t] & 0xFFFF0000u), acc.y);
            }
        }
        for (; j + 8 <= deg; j += 8) {
            float a[8]; int s[8];
            #pragma unroll
            for (int t = 0; t < 8; ++t) {
                a[t] = __shfl(alpha, j + t, 32);
                s[t] = __shfl(s_l, j + t, 32);
            }
            unsigned w[8];
            #pragma unroll
            for (int t = 0; t < 8; ++t)
                w[t] = *(const unsigned*)(vb + (size_t)s[t] * 64 + 2 * lane);
            #pragma unroll
            for (int t = 0; t < 8; ++t) {
                acc.x = fmaf(a[t], __uint_as_float(w[t] << 16), acc.x);
                acc.y = fmaf(a[t], __uint_as_float(w[t] & 0xFFFF0000u), acc.y);
            }
        }
        for (; j + 4 <= deg; j += 4) {
            float a[4]; int s[4];
            #pragma unroll
            for (int t = 0; t < 4; ++t) {
                a[t] = __shfl(alpha, j + t, 32);
                s[t] = __shfl(s_l, j + t, 32);
            }
            unsigned w[4];
            #pragma unroll
            for (int t = 0; t < 4; ++t)
                w[t] = *(const unsigned*)(vb + (size_t)s[t] * 64 + 2 * lane);
            #pragma unroll
            for (int t = 0; t < 4; ++t) {
                acc.x = fmaf(a[t], __uint_as_float(w[t] << 16), acc.x);
                acc.y = fmaf(a[t], __uint_as_float(w[t] & 0xFFFF0000u), acc.y);
            }
        }
        for (; j < deg; ++j) {
            float a = __shfl(alpha, j, 32);
            int   s = __shfl(s_l, j, 32);
            unsigned w = *(const unsigned*)(vb + (size_t)s * 64 + 2 * lane);
            acc.x = fmaf(a, __uint_as_float(w << 16), acc.x);
            acc.y = fmaf(a, __uint_as_float(w & 0xFFFF0000u), acc.y);
        }
    } else {
        // rare fallback (deg > 32): strided scores through csr_exp, 32 lanes
        float m = -__builtin_inff();
        for (int j = start + lane; j < end; j += 32) {
            int s = csr_src[j];
            float sc = dot64_q2_bf16(qreg, kb + (size_t)s * 64) * 0.125f;
            csr_exp[j] = sc;
            m = fmaxf(m, sc);
        }
        #pragma unroll
        for (int off = 1; off < 32; off <<= 1) m = fmaxf(m, __shfl_xor(m, off, 32));

        float ssum = 0.f;
        for (int j = start + lane; j < end; j += 32) {
            float ex = __expf(csr_exp[j] - m);
            csr_exp[j] = ex;
            ssum += ex;
        }
        #pragma unroll
        for (int off = 1; off < 32; off <<= 1) ssum += __shfl_xor(ssum, off, 32);
        float inv = 1.f / (ssum + 1e-16f);

        for (int j = start; j < end; ++j) {
            int s   = csr_src[j];
            float a = csr_exp[j] * inv;
            unsigned w = *(const unsigned*)(vb + (size_t)s * 64 + 2 * lane);
            acc.x = fmaf(a, __uint_as_float(w << 16), acc.x);
            acc.y = fmaf(a, __uint_as_float(w & 0xFFFF0000u), acc.y);
        }
    }

    hv.x = fmaxf(hv.x + acc.x, 0.f);
    hv.y = fmaxf(hv.y + acc.y, 0.f);
    *(float2*)(hout + ob) = hv;
}

// ============ pool + MLP ============
__global__ void zero_f(float* p, int n) {
    int i = blockIdx.x * blockDim.x + threadIdx.x;
    if (i < n) p[i] = 0.f;
}

__global__ void pool_kernel(const float* __restrict__ h, const int* __restrict__ batch,
                            float* __restrict__ pooled, int N)
{
    int col = threadIdx.x & 63;
    int rg  = threadIdx.x >> 6;
    int base = blockIdx.x * 128;
    int end  = base + 128; if (end > N) end = N;
    int gcur = -1; float acc = 0.f;
    for (int i = base + rg; i < end; i += 4) {
        int g = batch[i];
        if (g != gcur) {
            if (gcur >= 0) atomicAdd(&pooled[gcur * 64 + col], acc);
            gcur = g; acc = 0.f;
        }
        acc += h[(size_t)i * 64 + col];
    }
    if (gcur >= 0) atomicAdd(&pooled[gcur * 64 + col], acc);
}

__global__ void mlp1(const float* __restrict__ pooled, const float* __restrict__ W1,
                     const float* __restrict__ b1, float* __restrict__ hidden)
{
    int idx = blockIdx.x * blockDim.x + threadIdx.x;
    if (idx >= N_GRAPHS * 64) return;
    int g = idx >> 6, c = idx & 63;
    float acc = b1[c];
    for (int kk = 0; kk < 64; ++kk)
        acc = fmaf(pooled[g * 64 + kk], W1[kk * 64 + c], acc);
    hidden[idx] = fmaxf(acc, 0.f);
}

__global__ void mlp2(const float* __restrict__ hidden, const float* __restrict__ W2,
                     const float* __restrict__ b2, float* __restrict__ out)
{
    int idx = blockIdx.x * blockDim.x + threadIdx.x;
    if (idx >= N_GRAPHS * 16) return;
    int g = idx >> 4, c = idx & 15;
    float acc = b2[c];
    for (int kk = 0; kk < 64; ++kk)
        acc = fmaf(hidden[g * 64 + kk], W2[kk * 16 + c], acc);
    out[idx] = acc;
}

extern "C" void kernel_launch(void* const* d_in, const int* in_sizes, int n_in,
                              void* d_out, int out_size, void* d_ws, size_t ws_size,
                              hipStream_t stream)
{
    const float* x   = (const float*)d_in[0];
    const float* Wq0 = (const float*)d_in[1];  const float* bq0 = (const float*)d_in[2];
    const float* Wk0 = (const float*)d_in[3];  const float* bk0 = (const float*)d_in[4];
    const float* Wv0 = (const float*)d_in[5];  const float* bv0 = (const float*)d_in[6];
    const float* Ws0 = (const float*)d_in[7];  const float* bs0 = (const float*)d_in[8];
    const float* Wqs = (const float*)d_in[9];  const float* bqs = (const float*)d_in[10];
    const float* Wks = (const float*)d_in[11]; const float* bks = (const float*)d_in[12];
    const float* Wvs = (const float*)d_in[13]; const float* bvs = (const float*)d_in[14];
    const float* Wss = (const float*)d_in[15]; const float* bss = (const float*)d_in[16];
    const float* W1  = (const float*)d_in[17]; const float* b1  = (const float*)d_in[18];
    const float* W2  = (const float*)d_in[19]; const float* b2  = (const float*)d_in[20];
    const int*   ei  = (const int*)d_in[21];
    const int*   batch = (const int*)d_in[22];
    float* out = (float*)d_out;

    const int* src = ei;
    const int* dst = ei + N_EDGES;

    const size_t NH = (size_t)N_NODES * 64;
    float* q        = (float*)d_ws;
    float* hA       = q + NH;
    float* hB       = hA + NH;
    float* csr_exp  = hB + NH;                      // E floats (fallback only)
    int*   csr_src  = (int*)(csr_exp + N_EDGES);    // E ints
    int*   rank     = csr_src + N_EDGES;            // E ints
    unsigned short* kb = (unsigned short*)(rank + N_EDGES);  // NH bf16
    unsigned short* vb = kb + NH;                            // NH bf16
    int*   row_start= (int*)(vb + NH);              // N_NODES+1
    int*   counts   = row_start + N_NODES + 1;      // N_NODES
    int*   blockSums= counts + N_NODES;             // 512
    float* pooled   = (float*)(blockSums + 512);
    float* hidden   = pooled + N_GRAPHS * 64;

    struct LW { const float *Wq,*bq,*Wk,*bk,*Wv,*bv,*Ws,*bs; };
    LW lw[3] = {
        { Wq0, bq0, Wk0, bk0, Wv0, bv0, Ws0, bs0 },
        { Wqs, bqs, Wks, bks, Wvs, bvs, Wss, bss },
        { Wqs + 4096, bqs + 64, Wks + 4096, bks + 64, Wvs + 4096, bvs + 64, Wss + 4096, bss + 64 }
    };

    const int nodeBlocks = (N_NODES + 255) / 256;
    const int scanBlocks = (N_NODES + 255) / 256;   // 391
    const int rowTiles   = (N_NODES + 63) / 64;     // 1563
    const int gemmBlocks = 4 * rowTiles;            // 6252
    const int scatBlocks = (N_EDGES / 4 + 255) / 256;

    // ---- zero counts, then fused {count_rank(first) | layer-0 GEMM} ----
    zero_i<<<nodeBlocks, 256, 0, stream>>>(counts, N_NODES);
    gemm0_count<<<COUNT_BLOCKS + gemmBlocks, 256, 0, stream>>>(
        x, N_NODES,
        lw[0].Wq, lw[0].bq, lw[0].Wk, lw[0].bk, lw[0].Wv, lw[0].bv, lw[0].Ws, lw[0].bs,
        q, kb, vb, hA,
        dst, counts, rank, N_EDGES);

    // ---- scan + atomic-free scatter ----
    scan1<<<scanBlocks, 256, 0, stream>>>(counts, counts, blockSums, N_NODES);
    scan2<<<1, 512, 0, stream>>>(blockSums, scanBlocks);
    scan3<<<(N_NODES + 256) / 256, 256, 0, stream>>>(counts, blockSums, row_start,
                                                     N_NODES, N_EDGES);
    csr_scatter<<<scatBlocks, 256, 0, stream>>>(src, dst, rank, row_start, csr_src, N_EDGES);

    // ---- layer 0 attention ----
    node_attn<<<(N_NODES + 7) / 8, 256, 0, stream>>>(q, kb, vb, csr_src, row_start,
                                                     csr_exp, hA, N_NODES);

    // ---- layers 1..2 ----
    const dim3 gemmGrid(4, rowTiles);
    for (int L = 1; L < 3; ++L) {
        const float* hin = (L == 1) ? hA : hB;
        float* hou       = (L == 1) ? hB : hA;
        qkvs_gemm<HID><<<gemmGrid, 256, 0, stream>>>(hin, N_NODES,
            lw[L].Wq, lw[L].bq, lw[L].Wk, lw[L].bk, lw[L].Wv, lw[L].bv, lw[L].Ws, lw[L].bs,
            q, kb, vb, hou);
        node_attn<<<(N_NODES + 7) / 8, 256, 0, stream>>>(q, kb, vb, csr_src, row_start,
                                                         csr_exp, hou, N_NODES);
    }

    // ---- pool + MLP ----
    zero_f<<<(N_GRAPHS * 64 + 255) / 256, 256, 0, stream>>>(pooled, N_GRAPHS * 64);
    pool_kernel<<<(N_NODES + 127) / 128, 256, 0, stream>>>(hA, batch, pooled, N_NODES);
    mlp1<<<(N_GRAPHS * 64 + 255) / 256, 256, 0, stream>>>(pooled, W1, b1, hidden);
    mlp2<<<(N_GRAPHS * 16 + 255) / 256, 256, 0, stream>>>(hidden, W2, b2, out);
}

// Round 23
// 576.669 us; speedup vs baseline: 1.0242x; 1.0242x over previous
//
#include <hip/hip_runtime.h>
#include <hip/hip_bf16.h>

#define N_NODES 100000
#define N_EDGES 1600000
#define IN_DIM  128
#define HID     64
#define N_GRAPHS 500

// bf16 helpers (RNE pack, shift unpack)
__device__ inline unsigned short f2bf(float f) {
    unsigned u = __float_as_uint(f);
    u += 0x7FFFu + ((u >> 16) & 1u);
    return (unsigned short)(u >> 16);
}
__device__ inline float bf2f(unsigned short b) {
    return __uint_as_float(((unsigned)b) << 16);
}

// dot(q[node], k_row) with q distributed 2 elems/lane over a 32-lane group:
// lane l holds q[2l] (qreg.x), q[2l+1] (qreg.y). k_row local to this lane.
__device__ inline float dot64_q2_bf16(float2 qreg, const unsigned short* __restrict__ krow) {
    const uint4* kp = (const uint4*)krow;
    uint4 kr[8];
    #pragma unroll
    for (int i = 0; i < 8; ++i) kr[i] = kp[i];
    float dot = 0.f;
    #pragma unroll
    for (int i = 0; i < 8; ++i) {
        #pragma unroll
        for (int c = 0; c < 4; ++c) {
            unsigned w = (&kr[i].x)[c];          // cols 8i+2c, 8i+2c+1
            float qa = __shfl(qreg.x, 4 * i + c, 32);
            float qb = __shfl(qreg.y, 4 * i + c, 32);
            dot = fmaf(qa, __uint_as_float(w << 16), dot);
            dot = fmaf(qb, __uint_as_float(w & 0xFFFF0000u), dot);
        }
    }
    return dot;
}

// ============ shared GEMM body (64x64 C-tile of ONE matrix; 4x4 micro-tile) ====
template<int DIN>
__device__ inline void gemm_body(
    int by, int ty_blk,
    const float* __restrict__ x, int N,
    const float* __restrict__ Wq, const float* __restrict__ bq,
    const float* __restrict__ Wk, const float* __restrict__ bk,
    const float* __restrict__ Wv, const float* __restrict__ bv,
    const float* __restrict__ Ws, const float* __restrict__ bs,
    float* __restrict__ q, unsigned short* __restrict__ kb,
    unsigned short* __restrict__ vb, float* __restrict__ hout)
{
    constexpr int BM = 64, BK = 32;
    __shared__ float As[BK][BM + 1];
    __shared__ float Bs[BK][64];

    const float* W    = (by == 0) ? Wq : (by == 1) ? Wk : (by == 2) ? Wv : Ws;
    const float* bias = (by == 0) ? bq : (by == 1) ? bk : (by == 2) ? bv : bs;

    const int row0 = ty_blk * BM;
    const int tid  = threadIdx.x;
    const int tx   = (tid & 15) * 4;
    const int ty   = (tid >> 4) * 4;

    float acc[4][4] = {};

    for (int k0 = 0; k0 < DIN; k0 += BK) {
        #pragma unroll
        for (int h = 0; h < 2; ++h) {
            int idx = tid + h * 256;
            int r   = idx >> 3, c4 = idx & 7;
            int gr  = row0 + r;
            float4 val = (gr < N) ? *(const float4*)(x + (size_t)gr * DIN + k0 + c4 * 4)
                                  : make_float4(0.f, 0.f, 0.f, 0.f);
            int kk = c4 * 4;
            As[kk + 0][r] = val.x;
            As[kk + 1][r] = val.y;
            As[kk + 2][r] = val.z;
            As[kk + 3][r] = val.w;
        }
        #pragma unroll
        for (int h = 0; h < 2; ++h) {
            int kr = (tid >> 4) + h * 16;
            int n4 = (tid & 15) * 4;
            *(float4*)(&Bs[kr][n4]) = *(const float4*)(W + (size_t)(k0 + kr) * 64 + n4);
        }
        __syncthreads();

        #pragma unroll
        for (int kk = 0; kk < BK; ++kk) {
            float4 a = *(const float4*)(&As[kk][ty]);
            float4 b = *(const float4*)(&Bs[kk][tx]);
            acc[0][0] = fmaf(a.x, b.x, acc[0][0]);
            acc[0][1] = fmaf(a.x, b.y, acc[0][1]);
            acc[0][2] = fmaf(a.x, b.z, acc[0][2]);
            acc[0][3] = fmaf(a.x, b.w, acc[0][3]);
            acc[1][0] = fmaf(a.y, b.x, acc[1][0]);
            acc[1][1] = fmaf(a.y, b.y, acc[1][1]);
            acc[1][2] = fmaf(a.y, b.z, acc[1][2]);
            acc[1][3] = fmaf(a.y, b.w, acc[1][3]);
            acc[2][0] = fmaf(a.z, b.x, acc[2][0]);
            acc[2][1] = fmaf(a.z, b.y, acc[2][1]);
            acc[2][2] = fmaf(a.z, b.z, acc[2][2]);
            acc[2][3] = fmaf(a.z, b.w, acc[2][3]);
            acc[3][0] = fmaf(a.w, b.x, acc[3][0]);
            acc[3][1] = fmaf(a.w, b.y, acc[3][1]);
            acc[3][2] = fmaf(a.w, b.z, acc[3][2]);
            acc[3][3] = fmaf(a.w, b.w, acc[3][3]);
        }
        __syncthreads();
    }

    float4 bv4 = *(const float4*)(bias + tx);
    if (by == 1 || by == 2) {
        unsigned short* op = (by == 1) ? kb : vb;
        #pragma unroll
        for (int i = 0; i < 4; ++i) {
            int row = row0 + ty + i;
            if (row < N) {
                ushort4 pk;
                pk.x = f2bf(acc[i][0] + bv4.x);
                pk.y = f2bf(acc[i][1] + bv4.y);
                pk.z = f2bf(acc[i][2] + bv4.z);
                pk.w = f2bf(acc[i][3] + bv4.w);
                *(ushort4*)(op + (size_t)row * 64 + tx) = pk;
            }
        }
    } else {
        float* op = (by == 0) ? q : hout;
        #pragma unroll
        for (int i = 0; i < 4; ++i) {
            int row = row0 + ty + i;
            if (row < N) {
                float4 o = make_float4(acc[i][0] + bv4.x, acc[i][1] + bv4.y,
                                       acc[i][2] + bv4.z, acc[i][3] + bv4.w);
                *(float4*)(op + (size_t)row * 64 + tx) = o;
            }
        }
    }
}

// ============ CSR build ============
__global__ void zero_i(int* p, int n) {
    int i = blockIdx.x * blockDim.x + threadIdx.x;
    if (i < n) p[i] = 0;
}

#define COUNT_BLOCKS 1024

// layer-0 GEMM fused with count_rank (count blocks first, grid-stride).
__global__ __launch_bounds__(256) void gemm0_count(
    const float* __restrict__ x, int N,
    const float* __restrict__ Wq, const float* __restrict__ bq,
    const float* __restrict__ Wk, const float* __restrict__ bk,
    const float* __restrict__ Wv, const float* __restrict__ bv,
    const float* __restrict__ Ws, const float* __restrict__ bs,
    float* __restrict__ q, unsigned short* __restrict__ kb,
    unsigned short* __restrict__ vb, float* __restrict__ hout,
    const int* __restrict__ dst, int* __restrict__ counts,
    int* __restrict__ rank, int E)
{
    int bi = blockIdx.x;
    if (bi < COUNT_BLOCKS) {
        for (int e = bi * 256 + threadIdx.x; e < E; e += COUNT_BLOCKS * 256)
            rank[e] = atomicAdd(&counts[dst[e]], 1);
    } else {
        int gb = bi - COUNT_BLOCKS;
        gemm_body<IN_DIM>(gb & 3, gb >> 2, x, N, Wq, bq, Wk, bk, Wv, bv, Ws, bs,
                          q, kb, vb, hout);
    }
}

__global__ void scan1(const int* __restrict__ counts, int* __restrict__ pre,
                      int* __restrict__ blockSums, int n) {
    __shared__ int tmp[256];
    int tid = threadIdx.x;
    int i = blockIdx.x * 256 + tid;
    int v = (i < n) ? counts[i] : 0;
    tmp[tid] = v; __syncthreads();
    int acc = v;
    for (int off = 1; off < 256; off <<= 1) {
        int add = (tid >= off) ? tmp[tid - off] : 0;
        __syncthreads();
        acc += add; tmp[tid] = acc;
        __syncthreads();
    }
    if (i < n) pre[i] = acc - v;
    if (tid == 255) blockSums[blockIdx.x] = acc;
}

__global__ void scan2(int* blockSums, int nb) {
    __shared__ int tmp[512];
    int tid = threadIdx.x;
    int v = (tid < nb) ? blockSums[tid] : 0;
    tmp[tid] = v; __syncthreads();
    int acc = v;
    for (int off = 1; off < 512; off <<= 1) {
        int add = (tid >= off) ? tmp[tid - off] : 0;
        __syncthreads();
        acc += add; tmp[tid] = acc;
        __syncthreads();
    }
    if (tid < nb) blockSums[tid] = acc - v;
}

__global__ void scan3(const int* __restrict__ pre, const int* __restrict__ blockSums,
                      int* __restrict__ row_start, int n, int E) {
    int i = blockIdx.x * blockDim.x + threadIdx.x;
    if (i < n) {
        row_start[i] = pre[i] + blockSums[i >> 8];
    } else if (i == n) {
        row_start[n] = E;
    }
}

// atomic-free scatter: csr_src[row_start[dst] + rank] = src
__global__ void csr_scatter(const int* __restrict__ src, const int* __restrict__ dst,
                            const int* __restrict__ rank, const int* __restrict__ row_start,
                            int* __restrict__ csr_src, int E) {
    int e = blockIdx.x * blockDim.x + threadIdx.x;
    if (e >= E) return;
    csr_src[row_start[dst[e]] + rank[e]] = src[e];
}

// ============ standalone qkvs GEMM (layers 1..2) ============
template<int DIN>
__global__ __launch_bounds__(256) void qkvs_gemm(
    const float* __restrict__ x, int N,
    const float* __restrict__ Wq, const float* __restrict__ bq,
    const float* __restrict__ Wk, const float* __restrict__ bk,
    const float* __restrict__ Wv, const float* __restrict__ bv,
    const float* __restrict__ Ws, const float* __restrict__ bs,
    float* __restrict__ q, unsigned short* __restrict__ kb,
    unsigned short* __restrict__ vb, float* __restrict__ hout)
{
    gemm_body<DIN>(blockIdx.x, blockIdx.y, x, N, Wq, bq, Wk, bk, Wv, bv, Ws, bs,
                   q, kb, vb, hout);
}

// ============ fused scores + softmax + aggregation + skip + relu ============
// TWO nodes per wave (32 lanes each): 2x loads in flight for both the k-row
// score gather and the v-row PV gather, same total traffic. Lane l of a group
// holds q/output cols 2l, 2l+1. deg<=32 fast path (99.98% of Poisson(16)).
__global__ __launch_bounds__(256) void node_attn(
    const float* __restrict__ q, const unsigned short* __restrict__ kb,
    const unsigned short* __restrict__ vb,
    const int* __restrict__ csr_src, const int* __restrict__ row_start,
    float* __restrict__ csr_exp, float* __restrict__ hout, int N)
{
    int node = blockIdx.x * 8 + (threadIdx.x >> 5);
    int lane = threadIdx.x & 31;
    if (node >= N) return;
    int start = row_start[node], end = row_start[node + 1];
    int deg = end - start;
    size_t ob = (size_t)node * 64 + 2 * lane;

    float2 hv = *(const float2*)(hout + ob);   // skip path
    if (deg == 0) {
        hv.x = fmaxf(hv.x, 0.f); hv.y = fmaxf(hv.y, 0.f);
        *(float2*)(hout + ob) = hv;
        return;
    }

    float2 qreg = *(const float2*)(q + ob);    // q[node][2l..2l+1], coalesced
    float2 acc = make_float2(0.f, 0.f);

    if (deg <= 32) {
        int s_l = (lane < deg) ? csr_src[start + lane] : 0;
        float dot = dot64_q2_bf16(qreg, kb + (size_t)s_l * 64);
        float sc = (lane < deg) ? dot * 0.125f : -__builtin_inff();

        float m = sc;
        #pragma unroll
        for (int off = 1; off < 32; off <<= 1) m = fmaxf(m, __shfl_xor(m, off, 32));

        float ex = __expf(sc - m);     // lanes >= deg: exp(-inf)=0
        float ssum = ex;
        #pragma unroll
        for (int off = 1; off < 32; off <<= 1) ssum += __shfl_xor(ssum, off, 32);
        float alpha = ex * (1.f / (ssum + 1e-16f));

        int j = 0;
        for (; j + 16 <= deg; j += 16) {
            float a[16]; int s[16];
            #pragma unroll
            for (int t = 0; t < 16; ++t) {
                a[t] = __shfl(alpha, j + t, 32);
                s[t] = __shfl(s_l, j + t, 32);
            }
            unsigned w[16];
            #pragma unroll
            for (int t = 0; t < 16; ++t)
                w[t] = *(const unsigned*)(vb + (size_t)s[t] * 64 + 2 * lane);
            #pragma unroll
            for (int t = 0; t < 16; ++t) {
                acc.x = fmaf(a[t], __uint_as_float(w[t] << 16), acc.x);
                acc.y = fmaf(a[t], __uint_as_float(w[t] & 0xFFFF0000u), acc.y);
            }
        }
        for (; j + 8 <= deg; j += 8) {
            float a[8]; int s[8];
            #pragma unroll
            for (int t = 0; t < 8; ++t) {
                a[t] = __shfl(alpha, j + t, 32);
                s[t] = __shfl(s_l, j + t, 32);
            }
            unsigned w[8];
            #pragma unroll
            for (int t = 0; t < 8; ++t)
                w[t] = *(const unsigned*)(vb + (size_t)s[t] * 64 + 2 * lane);
            #pragma unroll
            for (int t = 0; t < 8; ++t) {
                acc.x = fmaf(a[t], __uint_as_float(w[t] << 16), acc.x);
                acc.y = fmaf(a[t], __uint_as_float(w[t] & 0xFFFF0000u), acc.y);
            }
        }
        for (; j + 4 <= deg; j += 4) {
            float a[4]; int s[4];
            #pragma unroll
            for (int t = 0; t < 4; ++t) {
                a[t] = __shfl(alpha, j + t, 32);
                s[t] = __shfl(s_l, j + t, 32);
            }
            unsigned w[4];
            #pragma unroll
            for (int t = 0; t < 4; ++t)
                w[t] = *(const unsigned*)(vb + (size_t)s[t] * 64 + 2 * lane);
            #pragma unroll
            for (int t = 0; t < 4; ++t) {
                acc.x = fmaf(a[t], __uint_as_float(w[t] << 16), acc.x);
                acc.y = fmaf(a[t], __uint_as_float(w[t] & 0xFFFF0000u), acc.y);
            }
        }
        for (; j < deg; ++j) {
            float a = __shfl(alpha, j, 32);
            int   s = __shfl(s_l, j, 32);
            unsigned w = *(const unsigned*)(vb + (size_t)s * 64 + 2 * lane);
            acc.x = fmaf(a, __uint_as_float(w << 16), acc.x);
            acc.y = fmaf(a, __uint_as_float(w & 0xFFFF0000u), acc.y);
        }
    } else {
        // rare fallback (deg > 32): strided scores through csr_exp, 32 lanes
        float m = -__builtin_inff();
        for (int j = start + lane; j < end; j += 32) {
            int s = csr_src[j];
            float sc = dot64_q2_bf16(qreg, kb + (size_t)s * 64) * 0.125f;
            csr_exp[j] = sc;
            m = fmaxf(m, sc);
        }
        #pragma unroll
        for (int off = 1; off < 32; off <<= 1) m = fmaxf(m, __shfl_xor(m, off, 32));

        float ssum = 0.f;
        for (int j = start + lane; j < end; j += 32) {
            float ex = __expf(csr_exp[j] - m);
            csr_exp[j] = ex;
            ssum += ex;
        }
        #pragma unroll
        for (int off = 1; off < 32; off <<= 1) ssum += __shfl_xor(ssum, off, 32);
        float inv = 1.f / (ssum + 1e-16f);

        for (int j = start; j < end; ++j) {
            int s   = csr_src[j];
            float a = csr_exp[j] * inv;
            unsigned w = *(const unsigned*)(vb + (size_t)s * 64 + 2 * lane);
            acc.x = fmaf(a, __uint_as_float(w << 16), acc.x);
            acc.y = fmaf(a, __uint_as_float(w & 0xFFFF0000u), acc.y);
        }
    }

    hv.x = fmaxf(hv.x + acc.x, 0.f);
    hv.y = fmaxf(hv.y + acc.y, 0.f);
    *(float2*)(hout + ob) = hv;
}

// ============ pool + MLP ============
__global__ void zero_f(float* p, int n) {
    int i = blockIdx.x * blockDim.x + threadIdx.x;
    if (i < n) p[i] = 0.f;
}

__global__ void pool_kernel(const float* __restrict__ h, const int* __restrict__ batch,
                            float* __restrict__ pooled, int N)
{
    int col = threadIdx.x & 63;
    int rg  = threadIdx.x >> 6;
    int base = blockIdx.x * 128;
    int end  = base + 128; if (end > N) end = N;
    int gcur = -1; float acc = 0.f;
    for (int i = base + rg; i < end; i += 4) {
        int g = batch[i];
        if (g != gcur) {
            if (gcur >= 0) atomicAdd(&pooled[gcur * 64 + col], acc);
            gcur = g; acc = 0.f;
        }
        acc += h[(size_t)i * 64 + col];
    }
    if (gcur >= 0) atomicAdd(&pooled[gcur * 64 + col], acc);
}

__global__ void mlp1(const float* __restrict__ pooled, const float* __restrict__ W1,
                     const float* __restrict__ b1, float* __restrict__ hidden)
{
    int idx = blockIdx.x * blockDim.x + threadIdx.x;
    if (idx >= N_GRAPHS * 64) return;
    int g = idx >> 6, c = idx & 63;
    float acc = b1[c];
    for (int kk = 0; kk < 64; ++kk)
        acc = fmaf(pooled[g * 64 + kk], W1[kk * 64 + c], acc);
    hidden[idx] = fmaxf(acc, 0.f);
}

__global__ void mlp2(const float* __restrict__ hidden, const float* __restrict__ W2,
                     const float* __restrict__ b2, float* __restrict__ out)
{
    int idx = blockIdx.x * blockDim.x + threadIdx.x;
    if (idx >= N_GRAPHS * 16) return;
    int g = idx >> 4, c = idx & 15;
    float acc = b2[c];
    for (int kk = 0; kk < 64; ++kk)
        acc = fmaf(hidden[g * 64 + kk], W2[kk * 16 + c], acc);
    out[idx] = acc;
}

extern "C" void kernel_launch(void* const* d_in, const int* in_sizes, int n_in,
                              void* d_out, int out_size, void* d_ws, size_t ws_size,
                              hipStream_t stream)
{
    const float* x   = (const float*)d_in[0];
    const float* Wq0 = (const float*)d_in[1];  const float* bq0 = (const float*)d_in[2];
    const float* Wk0 = (const float*)d_in[3];  const float* bk0 = (const float*)d_in[4];
    const float* Wv0 = (const float*)d_in[5];  const float* bv0 = (const float*)d_in[6];
    const float* Ws0 = (const float*)d_in[7];  const float* bs0 = (const float*)d_in[8];
    const float* Wqs = (const float*)d_in[9];  const float* bqs = (const float*)d_in[10];
    const float* Wks = (const float*)d_in[11]; const float* bks = (const float*)d_in[12];
    const float* Wvs = (const float*)d_in[13]; const float* bvs = (const float*)d_in[14];
    const float* Wss = (const float*)d_in[15]; const float* bss = (const float*)d_in[16];
    const float* W1  = (const float*)d_in[17]; const float* b1  = (const float*)d_in[18];
    const float* W2  = (const float*)d_in[19]; const float* b2  = (const float*)d_in[20];
    const int*   ei  = (const int*)d_in[21];
    const int*   batch = (const int*)d_in[22];
    float* out = (float*)d_out;

    const int* src = ei;
    const int* dst = ei + N_EDGES;

    const size_t NH = (size_t)N_NODES * 64;
    float* q        = (float*)d_ws;
    float* hA       = q + NH;
    float* hB       = hA + NH;
    float* csr_exp  = hB + NH;                      // E floats (fallback only)
    int*   csr_src  = (int*)(csr_exp + N_EDGES);    // E ints
    int*   rank     = csr_src + N_EDGES;            // E ints
    unsigned short* kb = (unsigned short*)(rank + N_EDGES);  // NH bf16
    unsigned short* vb = kb + NH;                            // NH bf16
    int*   row_start= (int*)(vb + NH);              // N_NODES+1
    int*   counts   = row_start + N_NODES + 1;      // N_NODES
    int*   blockSums= counts + N_NODES;             // 512
    float* pooled   = (float*)(blockSums + 512);
    float* hidden   = pooled + N_GRAPHS * 64;

    struct LW { const float *Wq,*bq,*Wk,*bk,*Wv,*bv,*Ws,*bs; };
    LW lw[3] = {
        { Wq0, bq0, Wk0, bk0, Wv0, bv0, Ws0, bs0 },
        { Wqs, bqs, Wks, bks, Wvs, bvs, Wss, bss },
        { Wqs + 4096, bqs + 64, Wks + 4096, bks + 64, Wvs + 4096, bvs + 64, Wss + 4096, bss + 64 }
    };

    const int nodeBlocks = (N_NODES + 255) / 256;
    const int edgeBlocks = (N_EDGES + 255) / 256;
    const int scanBlocks = (N_NODES + 255) / 256;   // 391
    const int rowTiles   = (N_NODES + 63) / 64;     // 1563
    const int gemmBlocks = 4 * rowTiles;            // 6252

    // ---- zero counts, then fused {count_rank(first) | layer-0 GEMM} ----
    zero_i<<<nodeBlocks, 256, 0, stream>>>(counts, N_NODES);
    gemm0_count<<<COUNT_BLOCKS + gemmBlocks, 256, 0, stream>>>(
        x, N_NODES,
        lw[0].Wq, lw[0].bq, lw[0].Wk, lw[0].bk, lw[0].Wv, lw[0].bv, lw[0].Ws, lw[0].bs,
        q, kb, vb, hA,
        dst, counts, rank, N_EDGES);

    // ---- scan + atomic-free scatter ----
    scan1<<<scanBlocks, 256, 0, stream>>>(counts, counts, blockSums, N_NODES);
    scan2<<<1, 512, 0, stream>>>(blockSums, scanBlocks);
    scan3<<<(N_NODES + 256) / 256, 256, 0, stream>>>(counts, blockSums, row_start,
                                                     N_NODES, N_EDGES);
    csr_scatter<<<edgeBlocks, 256, 0, stream>>>(src, dst, rank, row_start, csr_src, N_EDGES);

    // ---- layer 0 attention ----
    node_attn<<<(N_NODES + 7) / 8, 256, 0, stream>>>(q, kb, vb, csr_src, row_start,
                                                     csr_exp, hA, N_NODES);

    // ---- layers 1..2 ----
    const dim3 gemmGrid(4, rowTiles);
    for (int L = 1; L < 3; ++L) {
        const float* hin = (L == 1) ? hA : hB;
        float* hou       = (L == 1) ? hB : hA;
        qkvs_gemm<HID><<<gemmGrid, 256, 0, stream>>>(hin, N_NODES,
            lw[L].Wq, lw[L].bq, lw[L].Wk, lw[L].bk, lw[L].Wv, lw[L].bv, lw[L].Ws, lw[L].bs,
            q, kb, vb, hou);
        node_attn<<<(N_NODES + 7) / 8, 256, 0, stream>>>(q, kb, vb, csr_src, row_start,
                                                         csr_exp, hou, N_NODES);
    }

    // ---- pool + MLP ----
    zero_f<<<(N_GRAPHS * 64 + 255) / 256, 256, 0, stream>>>(pooled, N_GRAPHS * 64);
    pool_kernel<<<(N_NODES + 127) / 128, 256, 0, stream>>>(hA, batch, pooled, N_NODES);
    mlp1<<<(N_GRAPHS * 64 + 255) / 256, 256, 0, stream>>>(pooled, W1, b1, hidden);
    mlp2<<<(N_GRAPHS * 16 + 255) / 256, 256, 0, stream>>>(hidden, W2, b2, out);
}